// Round 4
// baseline (107.049 us; speedup 1.0000x reference)
//
#include <hip/hip_runtime.h>
#include <hip/hip_bf16.h>
#include <math.h>

// SDGCN fused, split-bf16 MFMA, v4.
// = v2 (verified) with staging split/transposed hoisted to a pre-pass:
//   pre-pass writes Xh/Xl (row-major) and XTh/XTl (d-major) bf16 planes
//   to workspace; hot-loop staging is pure b128 copies (no VALU, no
//   scalar LDS writes). Compute structure identical to the passing v2.
//
// mfma_f32_16x16x32_bf16 layouts (m89/m92-verified):
//   A-frag: lane l holds A[l&15][(l>>4)*8+e]
//   B-frag: lane l holds B[(l>>4)*8+e][l&15]
//   C/D:    lane l, reg r holds C[(l>>4)*4+r][l&15]

typedef short bf16x8 __attribute__((ext_vector_type(8)));
typedef float f32x4  __attribute__((ext_vector_type(4)));

constexpr int kN  = 1024;
constexpr int kD  = 64;
constexpr int kKS = 72;   // K LDS row stride (shorts): QK b128 reads 2-way/free
constexpr int kVS = 40;   // Vt LDS row stride (shorts): PV b128 reads 2-way/free
constexpr int kHS = 68;   // H exchange row stride (floats)
constexpr size_t kPlane = 48u * 1024u * 64u;   // elements per bf16 plane

#define MFMA_BF16(a,b,c) __builtin_amdgcn_mfma_f32_16x16x32_bf16((a),(b),(c),0,0,0)

// truncation split: v = hi + lo (both bf16); product error ~2^-17
__device__ __forceinline__ void splitv(float v, short& h, short& l) {
  unsigned u = __float_as_uint(v);
  h = (short)(u >> 16);
  float hf = __uint_as_float(u & 0xFFFF0000u);
  l = (short)(__float_as_uint(v - hf) >> 16);
}

// ---------------- pre-pass: split X to bf16 hi/lo, row-major + transposed ----
__global__ __launch_bounds__(256)
void presplit(const float* __restrict__ X, short* __restrict__ Xh,
              short* __restrict__ Xl, short* __restrict__ XTh,
              short* __restrict__ XTl)
{
  __shared__ short Sh[64][68], Sl[64][68];
  const int t  = threadIdx.x;
  const int bt = blockIdx.x >> 4;
  const int mb = blockIdx.x & 15;
  const size_t base = (size_t)bt * 65536 + (size_t)mb * 64 * 64;   // elements

#pragma unroll
  for (int k = 0; k < 4; ++k) {
    int idx = t + k * 256;            // 0..1023 float4 chunks of the 64x64 tile
    int row = idx >> 4;
    int c4  = (idx & 15) * 4;
    float4 v = *(const float4*)(X + base + row * 64 + c4);
    short h0,l0,h1,l1,h2,l2,h3,l3;
    splitv(v.x, h0, l0); splitv(v.y, h1, l1);
    splitv(v.z, h2, l2); splitv(v.w, h3, l3);
    short4 hv = make_short4(h0, h1, h2, h3);
    short4 lv = make_short4(l0, l1, l2, l3);
    *(short4*)(Xh + base + row * 64 + c4) = hv;
    *(short4*)(Xl + base + row * 64 + c4) = lv;
    *(short4*)&Sh[row][c4] = hv;
    *(short4*)&Sl[row][c4] = lv;
  }
  __syncthreads();

  const size_t tbase = (size_t)bt * 65536 + (size_t)mb * 64;   // + d*1024 + m
#pragma unroll
  for (int k = 0; k < 2; ++k) {
    int idx = t + k * 256;            // 0..511 chunks of 8 m-elems
    int d   = idx >> 3;
    int m8  = (idx & 7) * 8;
    bf16x8 hv, lv;
#pragma unroll
    for (int j = 0; j < 8; ++j) { hv[j] = Sh[m8 + j][d]; lv[j] = Sl[m8 + j][d]; }
    *(bf16x8*)(XTh + tbase + (size_t)d * 1024 + m8) = hv;
    *(bf16x8*)(XTl + tbase + (size_t)d * 1024 + m8) = lv;
  }
}

// ---------------- main fused kernel ----------------
__global__ __launch_bounds__(256)
void sdgcn_mfma(const float* __restrict__ X, const float* __restrict__ A,
                const float* __restrict__ W, const float* __restrict__ gamma,
                const float* __restrict__ beta, float* __restrict__ out,
                const short* __restrict__ Xh, const short* __restrict__ Xl,
                const short* __restrict__ XTh, const short* __restrict__ XTl)
{
  __shared__ __align__(16) short Kh[32 * kKS], Kl[32 * kKS];   // K tile row-major
  __shared__ __align__(16) short Vth[64 * kVS], Vtl[64 * kVS]; // V tile transposed [d][m]
  __shared__ __align__(16) float Hs[4][16 * kHS];              // per-wave H exchange

  const int t    = threadIdx.x;
  const int wave = t >> 6;
  const int lane = t & 63;
  const int g    = lane >> 4;   // 0..3
  const int ql   = lane & 15;   // 0..15
  const int bt   = blockIdx.x >> 4;
  const int qt   = blockIdx.x & 15;
  const int qbase = qt * 64 + wave * 16;
  const size_t xb = (size_t)bt * 65536;

  // ---- Q fragments from pre-split planes: lane holds Q[qbase+ql][kk*32+g*8+e]
  bf16x8 qh[2], qlo[2];
#pragma unroll
  for (int kk = 0; kk < 2; ++kk) {
    const size_t qoff = xb + (size_t)(qbase + ql) * kD + kk * 32 + g * 8;
    qh[kk]  = *(const bf16x8*)(Xh + qoff);
    qlo[kk] = *(const bf16x8*)(Xl + qoff);
  }

  f32x4 o[4];   // o[c][r] = O[q=4g+r][d=16c+ql]
#pragma unroll
  for (int c = 0; c < 4; ++c) o[c] = {0.f, 0.f, 0.f, 0.f};
  float mrun = -INFINITY, Z = 0.f;

  // staging roles (pure copies from pre-split planes)
  const int smm = t >> 3;            // K: k-row 0..31
  const int sd8 = (t & 7) * 8;       // K: d 0..56
  const int vd  = t >> 2;            // Vt: d 0..63
  const int vm0 = (t & 3) * 8;       // Vt: m 0..24

  for (int ks = 0; ks < 32; ++ks) {
    const int kbase = ks * 32;
    __syncthreads();   // previous step's LDS reads complete
    {
      const size_t koff = xb + (size_t)(kbase + smm) * kD + sd8;
      *(bf16x8*)&Kh[smm * kKS + sd8] = *(const bf16x8*)(Xh + koff);
      *(bf16x8*)&Kl[smm * kKS + sd8] = *(const bf16x8*)(Xl + koff);
      const size_t voff = xb + (size_t)vd * 1024 + kbase + vm0;
      *(bf16x8*)&Vth[vd * kVS + vm0] = *(const bf16x8*)(XTh + voff);
      *(bf16x8*)&Vtl[vd * kVS + vm0] = *(const bf16x8*)(XTl + voff);
    }
    __syncthreads();

    // A-gate loads (consumed after P-exchange)
    const float* Ap = A + (size_t)(qbase + ql) * kN + kbase + 8 * g;
    const float4 ag0 = *(const float4*)Ap;
    const float4 ag1 = *(const float4*)(Ap + 4);

    // ---- QK^T swapped: lane holds S[q=ql][k=16tt+4g+r]
    f32x4 s[2];
#pragma unroll
    for (int tt = 0; tt < 2; ++tt) {
      const int krow = tt * 16 + ql;
      bf16x8 kh0 = *(const bf16x8*)&Kh[krow * kKS + g * 8];
      bf16x8 kh1 = *(const bf16x8*)&Kh[krow * kKS + 32 + g * 8];
      bf16x8 kl0 = *(const bf16x8*)&Kl[krow * kKS + g * 8];
      bf16x8 kl1 = *(const bf16x8*)&Kl[krow * kKS + 32 + g * 8];
      f32x4 acc = {0.f, 0.f, 0.f, 0.f};
      acc = MFMA_BF16(kh0, qh[0],  acc);
      acc = MFMA_BF16(kh1, qh[1],  acc);
      acc = MFMA_BF16(kh0, qlo[0], acc);
      acc = MFMA_BF16(kh1, qlo[1], acc);
      acc = MFMA_BF16(kl0, qh[0],  acc);
      acc = MFMA_BF16(kl1, qh[1],  acc);
      s[tt] = acc;
    }

    // ---- online softmax (always-rescale; stats per q=ql, replicated over g)
    float sm = s[0][0];
#pragma unroll
    for (int r = 1; r < 4; ++r) sm = fmaxf(sm, s[0][r]);
#pragma unroll
    for (int r = 0; r < 4; ++r) sm = fmaxf(sm, s[1][r]);
    sm = fmaxf(sm, __shfl_xor(sm, 16, 64));
    sm = fmaxf(sm, __shfl_xor(sm, 32, 64));
    const float nm = fmaxf(mrun, sm);
    const float f  = __expf(mrun - nm);   // 0 on first tile
    float p[2][4];
    float zt = 0.f;
#pragma unroll
    for (int tt = 0; tt < 2; ++tt)
#pragma unroll
      for (int r = 0; r < 4; ++r) { p[tt][r] = __expf(s[tt][r] - nm); zt += p[tt][r]; }
    zt += __shfl_xor(zt, 16, 64);
    zt += __shfl_xor(zt, 32, 64);
    Z = Z * f + zt;
    mrun = nm;

    // rescale O: factor for q=4g+r from lane 4g+r (g=0 copy)
#pragma unroll
    for (int r = 0; r < 4; ++r) {
      const float fr = __shfl(f, 4 * g + r, 64);
#pragma unroll
      for (int c = 0; c < 4; ++c) o[c][r] *= fr;
    }

    // ---- exchange P to PV A-frag layout: lane (ql,g) wants P[q=ql][k=8g+e]
    const int src0 = ((2 * (g & 1)) << 4) | ql;
    const int src1 = src0 + 16;
    float pa[8];
    const bool hihalf = (g >> 1) != 0;
#pragma unroll
    for (int r = 0; r < 4; ++r) {
      float a0 = __shfl(p[0][r], src0, 64);
      float a1 = __shfl(p[1][r], src0, 64);
      float b0 = __shfl(p[0][r], src1, 64);
      float b1 = __shfl(p[1][r], src1, 64);
      pa[r]     = hihalf ? a1 : a0;
      pa[r + 4] = hihalf ? b1 : b0;
    }
    // gate by A, split to bf16 hi/lo
    pa[0] *= ag0.x; pa[1] *= ag0.y; pa[2] *= ag0.z; pa[3] *= ag0.w;
    pa[4] *= ag1.x; pa[5] *= ag1.y; pa[6] *= ag1.z; pa[7] *= ag1.w;
    bf16x8 pah, pal;
#pragma unroll
    for (int e = 0; e < 8; ++e) { short hh, ll; splitv(pa[e], hh, ll); pah[e] = hh; pal[e] = ll; }

    // ---- PV: O[q][d] += P[q][k] V[k][d]; B-frag = Vt[d][8g..8g+7]
#pragma unroll
    for (int c = 0; c < 4; ++c) {
      const int d = c * 16 + ql;
      bf16x8 vh = *(const bf16x8*)&Vth[d * kVS + 8 * g];
      bf16x8 vl = *(const bf16x8*)&Vtl[d * kVS + 8 * g];
      o[c] = MFMA_BF16(pah, vh, o[c]);
      o[c] = MFMA_BF16(pah, vl, o[c]);
      o[c] = MFMA_BF16(pal, vh, o[c]);
    }
  }

  // ================= epilogue =================
  float invr[4];
#pragma unroll
  for (int r = 0; r < 4; ++r) {
    const float zq = __shfl(Z, 4 * g + r, 64);
    invr[r] = 1.0f / (8.0f * zq);   // sqrt(64) = 8
  }
  float* Hw = Hs[wave];
#pragma unroll
  for (int c = 0; c < 4; ++c)
#pragma unroll
    for (int r = 0; r < 4; ++r)
      Hw[(4 * g + r) * kHS + c * 16 + ql] = o[c][r] * invr[r];
  __syncthreads();

  // H A-frags: lane holds H[q=ql][kd = kk*32 + 8g + e]
  bf16x8 hh[2], hl[2];
#pragma unroll
  for (int kk = 0; kk < 2; ++kk) {
    const float* hp = &Hw[ql * kHS + kk * 32 + g * 8];
    float4 v0 = *(const float4*)hp;
    float4 v1 = *(const float4*)(hp + 4);
    float v[8] = {v0.x, v0.y, v0.z, v0.w, v1.x, v1.y, v1.z, v1.w};
#pragma unroll
    for (int e = 0; e < 8; ++e) { short a, b; splitv(v[e], a, b); hh[kk][e] = a; hl[kk][e] = b; }
  }

  // lin = H W^T; B-frag = W^T[kd][i] = W[i=16c+ql][kd=kk*32+8g+e]
  f32x4 lin[4];
#pragma unroll
  for (int c = 0; c < 4; ++c) {
    bf16x8 wh[2], wl[2];
#pragma unroll
    for (int kk = 0; kk < 2; ++kk) {
      const float* wp = W + (size_t)(c * 16 + ql) * kD + kk * 32 + g * 8;
      float4 v0 = *(const float4*)wp;
      float4 v1 = *(const float4*)(wp + 4);
      float v[8] = {v0.x, v0.y, v0.z, v0.w, v1.x, v1.y, v1.z, v1.w};
#pragma unroll
      for (int e = 0; e < 8; ++e) { short a, b; splitv(v[e], a, b); wh[kk][e] = a; wl[kk][e] = b; }
    }
    f32x4 acc = {0.f, 0.f, 0.f, 0.f};
    acc = MFMA_BF16(hh[0], wh[0], acc);
    acc = MFMA_BF16(hh[1], wh[1], acc);
    acc = MFMA_BF16(hh[0], wl[0], acc);
    acc = MFMA_BF16(hh[1], wl[1], acc);
    acc = MFMA_BF16(hl[0], wh[0], acc);
    acc = MFMA_BF16(hl[1], wh[1], acc);
    lin[c] = acc;
  }

  // relu + LN (var = E[x^2]-mu^2, ddof=0)
  float rl[4][4];
#pragma unroll
  for (int c = 0; c < 4; ++c)
#pragma unroll
    for (int r = 0; r < 4; ++r) rl[c][r] = fmaxf(lin[c][r], 0.f);

  float mu[4], rstd[4];
#pragma unroll
  for (int r = 0; r < 4; ++r) {
    float s1 = rl[0][r] + rl[1][r] + rl[2][r] + rl[3][r];
    float s2 = rl[0][r]*rl[0][r] + rl[1][r]*rl[1][r] + rl[2][r]*rl[2][r] + rl[3][r]*rl[3][r];
#pragma unroll
    for (int off = 1; off < 16; off <<= 1) {
      s1 += __shfl_xor(s1, off, 64);
      s2 += __shfl_xor(s2, off, 64);
    }
    mu[r] = s1 * (1.f / 64.f);
    const float var = s2 * (1.f / 64.f) - mu[r] * mu[r];
    rstd[r] = rsqrtf(var + 1e-5f);
  }

#pragma unroll
  for (int c = 0; c < 4; ++c) {
    const float gm = gamma[c * 16 + ql];
    const float bb = beta[c * 16 + ql];
#pragma unroll
    for (int r = 0; r < 4; ++r) {
      const int qrow = qbase + 4 * g + r;
      const size_t off = ((size_t)bt * kN + qrow) * kD + c * 16 + ql;
      out[off] = (rl[c][r] - mu[r]) * rstd[r] * gm + bb + X[off];
    }
  }
}

extern "C" void kernel_launch(void* const* d_in, const int* in_sizes, int n_in,
                              void* d_out, int out_size, void* d_ws, size_t ws_size,
                              hipStream_t stream) {
  const float* X     = (const float*)d_in[0];
  const float* A     = (const float*)d_in[1];
  const float* W     = (const float*)d_in[2];
  const float* gamma = (const float*)d_in[3];
  const float* beta  = (const float*)d_in[4];
  float* out = (float*)d_out;

  // workspace: 4 bf16 planes (25.2 MB)
  short* Xh  = (short*)d_ws;
  short* Xl  = Xh  + kPlane;
  short* XTh = Xl  + kPlane;
  short* XTl = XTh + kPlane;

  presplit<<<dim3(48 * 16), 256, 0, stream>>>(X, Xh, Xl, XTh, XTl);
  sdgcn_mfma<<<dim3(48 * 16), 256, 0, stream>>>(X, A, W, gamma, beta, out,
                                                Xh, Xl, XTh, XTl);
}

// Round 5
// 81.674 us; speedup vs baseline: 1.3107x; 1.3107x over previous
//
#include <hip/hip_runtime.h>
#include <hip/hip_bf16.h>
#include <math.h>

// SDGCN fused, v5: 32x32x16 MFMA + swapped QK (lane-local softmax) +
// in-block split-K (4 waves = 2 q-waves x 2 k-groups) + LDS merge +
// verified v2 16x16 epilogue per 16-row subtile.
//
// mfma_f32_32x32x16_bf16 layouts (m74/m101-verified C/D; standard A/B):
//   A-frag: lane l holds A[l&31][(l>>5)*8+e]
//   B-frag: lane l holds B[(l>>5)*8+e][l&31]
//   C/D:    lane l, reg r holds C[(r&3)+8*(r>>2)+4*(l>>5)][l&31]
// Swapped QK: D = mfma(K,Q) -> S[k][q], so per-q softmax stats are
// lane-local (q = l&31, replicated over l>=32).

typedef short bf16x8 __attribute__((ext_vector_type(8)));
typedef float f32x4  __attribute__((ext_vector_type(4)));
typedef float f32x16 __attribute__((ext_vector_type(16)));
typedef int   i32x4  __attribute__((ext_vector_type(4)));

constexpr int kN = 1024;
constexpr int kD = 64;
constexpr size_t kPlane = 48u * 1024u * 64u;

#define MFMA32(a,b,c) __builtin_amdgcn_mfma_f32_32x32x16_bf16((a),(b),(c),0,0,0)
#define MFMA16(a,b,c) __builtin_amdgcn_mfma_f32_16x16x32_bf16((a),(b),(c),0,0,0)

// truncation split: v = hi + lo (both bf16); product error ~2^-17
__device__ __forceinline__ void splitv(float v, short& h, short& l) {
  unsigned u = __float_as_uint(v);
  h = (short)(u >> 16);
  float hf = __uint_as_float(u & 0xFFFF0000u);
  l = (short)(__float_as_uint(v - hf) >> 16);
}

// pack two floats to (bf16(a) | bf16(b)<<16), truncation
__device__ __forceinline__ unsigned pkbf(float a, float b) {
  return (__float_as_uint(a) >> 16) | (__float_as_uint(b) & 0xFFFF0000u);
}

// ---------------- pre-pass (v4-verified): X -> bf16 hi/lo planes ----------
__global__ __launch_bounds__(256)
void presplit(const float* __restrict__ X, short* __restrict__ Xh,
              short* __restrict__ Xl, short* __restrict__ XTh,
              short* __restrict__ XTl)
{
  __shared__ short Sh[64][68], Sl[64][68];
  const int t  = threadIdx.x;
  const int bt = blockIdx.x >> 4;
  const int mb = blockIdx.x & 15;
  const size_t base = (size_t)bt * 65536 + (size_t)mb * 64 * 64;

#pragma unroll
  for (int k = 0; k < 4; ++k) {
    int idx = t + k * 256;
    int row = idx >> 4;
    int c4  = (idx & 15) * 4;
    float4 v = *(const float4*)(X + base + row * 64 + c4);
    short h0,l0,h1,l1,h2,l2,h3,l3;
    splitv(v.x, h0, l0); splitv(v.y, h1, l1);
    splitv(v.z, h2, l2); splitv(v.w, h3, l3);
    short4 hv = make_short4(h0, h1, h2, h3);
    short4 lv = make_short4(l0, l1, l2, l3);
    *(short4*)(Xh + base + row * 64 + c4) = hv;
    *(short4*)(Xl + base + row * 64 + c4) = lv;
    *(short4*)&Sh[row][c4] = hv;
    *(short4*)&Sl[row][c4] = lv;
  }
  __syncthreads();

  const size_t tbase = (size_t)bt * 65536 + (size_t)mb * 64;
#pragma unroll
  for (int k = 0; k < 2; ++k) {
    int idx = t + k * 256;
    int d   = idx >> 3;
    int m8  = (idx & 7) * 8;
    bf16x8 hv, lv;
#pragma unroll
    for (int j = 0; j < 8; ++j) { hv[j] = Sh[m8 + j][d]; lv[j] = Sl[m8 + j][d]; }
    *(bf16x8*)(XTh + tbase + (size_t)d * 1024 + m8) = hv;
    *(bf16x8*)(XTl + tbase + (size_t)d * 1024 + m8) = lv;
  }
}

// ---------------- main fused kernel ----------------
__global__ __launch_bounds__(256)
void sdgcn_v5(const float* __restrict__ X, const float* __restrict__ A,
              const float* __restrict__ W, const float* __restrict__ gamma,
              const float* __restrict__ beta, float* __restrict__ out,
              const short* __restrict__ Xh, const short* __restrict__ Xl,
              const short* __restrict__ XTh, const short* __restrict__ XTl)
{
  // LDS map (38912 B):
  //  [0, 18432): K tiles, per k-group 9216B: Kh[32*72], Kl[32*72] shorts
  //              (stride 72 shorts: b128 8-lane-group quads distinct)
  //              union (post-loop): stats aM[2][64], aZ[2][64], aF[3][64]
  //  [18432, 38912): Vt tiles, per group 10240B: Vth[64*40], Vtl[64*40]
  //              union (post-loop): Har[64][68] floats (merge + epilogue)
  __shared__ __align__(16) unsigned char LB[38912];

  const int t    = threadIdx.x;
  const int wave = t >> 6;
  const int lane = t & 63;
  const int kg   = wave >> 1;      // k-group 0/1
  const int qw   = wave & 1;       // q-wave 0/1 (32 rows each)
  const int half = lane >> 5;      // 0/1
  const int l31  = lane & 31;
  const int bt   = blockIdx.x >> 4;
  const int qt   = blockIdx.x & 15;
  const int qblk = qt * 64;
  const size_t xb = (size_t)bt * 65536;

  short* Khg  = (short*)(LB + kg * 9216);
  short* Klg  = Khg + 2304;
  short* Vthg = (short*)(LB + 18432 + kg * 10240);
  short* Vtlg = Vthg + 2560;
  float* Har  = (float*)(LB + 18432);   // [64][68]
  float* aM   = (float*)LB;             // [2][64]
  float* aZ   = aM + 128;
  float* aF   = aZ + 128;               // [3][64]: fa, fb, 1/(8Z*)

  // ---- Q B-frags: lane holds Q[qblk+qw*32+l31][16c + half*8 + e]
  const int qmine = qblk + qw * 32 + l31;
  bf16x8 qh[4], qlo[4];
#pragma unroll
  for (int c = 0; c < 4; ++c) {
    const size_t off = xb + (size_t)qmine * kD + 16 * c + half * 8;
    qh[c]  = *(const bf16x8*)(Xh + off);
    qlo[c] = *(const bf16x8*)(Xl + off);
  }

  f32x16 o0, o1;
#pragma unroll
  for (int r = 0; r < 16; ++r) { o0[r] = 0.f; o1[r] = 0.f; }
  float mrun = -INFINITY, Z = 0.f;

  const int tg = t & 127;   // thread within k-group (2 waves)

  auto ldK = [&](int kb, int j, bf16x8& h, bf16x8& l) {
    int ck = tg + 128 * j; int kr = ck >> 3; int kc = (ck & 7) * 8;
    size_t off = xb + (size_t)(kb + kr) * kD + kc;
    h = *(const bf16x8*)(Xh + off);
    l = *(const bf16x8*)(Xl + off);
  };
  auto ldV = [&](int kb, int j, bf16x8& h, bf16x8& l) {
    int cv = tg + 128 * j; int vd = cv >> 2; int vm = (cv & 3) * 8;
    size_t off = xb + (size_t)vd * 1024 + kb + vm;
    h = *(const bf16x8*)(XTh + off);
    l = *(const bf16x8*)(XTl + off);
  };
  auto stK = [&](int j, bf16x8 h, bf16x8 l) {
    int ck = tg + 128 * j; int kr = ck >> 3; int kc = (ck & 7) * 8;
    *(bf16x8*)&Khg[kr * 72 + kc] = h;
    *(bf16x8*)&Klg[kr * 72 + kc] = l;
  };
  auto stV = [&](int j, bf16x8 h, bf16x8 l) {
    int cv = tg + 128 * j; int vd = cv >> 2; int vm = (cv & 3) * 8;
    *(bf16x8*)&Vthg[vd * 40 + vm] = h;
    *(bf16x8*)&Vtlg[vd * 40 + vm] = l;
  };

  // prologue: stage first tile of this k-group
  {
    bf16x8 a0,a1,b0,b1,c0,c1,d0,d1;
    ldK(kg * 512, 0, a0, a1); ldK(kg * 512, 1, b0, b1);
    ldV(kg * 512, 0, c0, c1); ldV(kg * 512, 1, d0, d1);
    stK(0, a0, a1); stK(1, b0, b1); stV(0, c0, c1); stV(1, d0, d1);
  }
  __syncthreads();

  for (int ks = 0; ks < 16; ++ks) {
    const int kb = kg * 512 + ks * 32;

    // T14: issue next tile's global loads before compute
    bf16x8 nk0h,nk0l,nk1h,nk1l,nv0h,nv0l,nv1h,nv1l;
    const bool pfm = (ks + 1) < 16;
    if (pfm) {
      ldK(kb + 32, 0, nk0h, nk0l); ldK(kb + 32, 1, nk1h, nk1l);
      ldV(kb + 32, 0, nv0h, nv0l); ldV(kb + 32, 1, nv1h, nv1l);
    }

    // A gate values: agv[4j+i] = A[qmine][kb + 8j + 4*half + i]
    const float* Arow = A + (size_t)qmine * kN + kb + 4 * half;
    float4 ag0 = *(const float4*)(Arow);
    float4 ag1 = *(const float4*)(Arow + 8);
    float4 ag2 = *(const float4*)(Arow + 16);
    float4 ag3 = *(const float4*)(Arow + 24);
    float agv[16] = {ag0.x,ag0.y,ag0.z,ag0.w, ag1.x,ag1.y,ag1.z,ag1.w,
                     ag2.x,ag2.y,ag2.z,ag2.w, ag3.x,ag3.y,ag3.z,ag3.w};

    // ---- QK^T swapped: lane holds S[k_local(r,half)][q=l31]
    f32x16 sa;
#pragma unroll
    for (int r = 0; r < 16; ++r) sa[r] = 0.f;
#pragma unroll
    for (int c = 0; c < 4; ++c) {
      bf16x8 kh = *(const bf16x8*)&Khg[l31 * 72 + 16 * c + half * 8];
      bf16x8 kl = *(const bf16x8*)&Klg[l31 * 72 + 16 * c + half * 8];
      sa = MFMA32(kh, qh[c],  sa);
      sa = MFMA32(kh, qlo[c], sa);
      sa = MFMA32(kl, qh[c],  sa);
    }

    // ---- defer-max online softmax (stats lane-local, q = l31)
    float sm = sa[0];
#pragma unroll
    for (int r = 1; r < 16; ++r) sm = fmaxf(sm, sa[r]);
    sm = fmaxf(sm, __shfl_xor(sm, 32, 64));
    if (__any(sm > mrun + 8.f)) {
      const float nm = fmaxf(mrun, sm);
      const float f  = __expf(mrun - nm);   // 0 on first tile
      mrun = nm; Z *= f;
#pragma unroll
      for (int r = 0; r < 16; ++r) {
        const float fr = __shfl(f, (r & 3) + 8 * (r >> 2) + 4 * half, 64);
        o0[r] *= fr; o1[r] *= fr;
      }
    }
    float zt = 0.f;
    float pa[16];
#pragma unroll
    for (int r = 0; r < 16; ++r) {
      const float pv = __expf(sa[r] - mrun);
      zt += pv;
      pa[r] = pv * agv[r];
    }
    zt += __shfl_xor(zt, 32, 64);
    Z += zt;

    // ---- pack gated P to bf16 + cross-half exchange -> PV A-frags
    unsigned du[8], su[8];
#pragma unroll
    for (int j = 0; j < 8; ++j) du[j] = pkbf(pa[2*j], pa[2*j+1]);
#pragma unroll
    for (int j = 0; j < 8; ++j) su[j] = (unsigned)__shfl_xor((int)du[j], 32, 64);
    const bool lo = (half == 0);
    i32x4 w0, w1;
    w0[0] = lo ? du[0] : su[2]; w0[1] = lo ? du[1] : su[3];
    w0[2] = lo ? su[0] : du[2]; w0[3] = lo ? su[1] : du[3];
    w1[0] = lo ? du[4] : su[6]; w1[1] = lo ? du[5] : su[7];
    w1[2] = lo ? su[4] : du[6]; w1[3] = lo ? su[5] : du[7];
    bf16x8 pf0 = *(bf16x8*)&w0;   // k-chunk 0 (k=0..15)
    bf16x8 pf1 = *(bf16x8*)&w1;   // k-chunk 1 (k=16..31)

    // ---- PV: O[q][d] += P[q][k] V[k][d]  (P bf16-trunc; V hi+lo)
    {
      bf16x8 vh, vl;
      vh = *(const bf16x8*)&Vthg[l31 * 40 + half * 8];
      vl = *(const bf16x8*)&Vtlg[l31 * 40 + half * 8];
      o0 = MFMA32(pf0, vh, o0); o0 = MFMA32(pf0, vl, o0);
      vh = *(const bf16x8*)&Vthg[l31 * 40 + 16 + half * 8];
      vl = *(const bf16x8*)&Vtlg[l31 * 40 + 16 + half * 8];
      o0 = MFMA32(pf1, vh, o0); o0 = MFMA32(pf1, vl, o0);
      vh = *(const bf16x8*)&Vthg[(32 + l31) * 40 + half * 8];
      vl = *(const bf16x8*)&Vtlg[(32 + l31) * 40 + half * 8];
      o1 = MFMA32(pf0, vh, o1); o1 = MFMA32(pf0, vl, o1);
      vh = *(const bf16x8*)&Vthg[(32 + l31) * 40 + 16 + half * 8];
      vl = *(const bf16x8*)&Vtlg[(32 + l31) * 40 + 16 + half * 8];
      o1 = MFMA32(pf1, vh, o1); o1 = MFMA32(pf1, vl, o1);
    }

    __syncthreads();   // all reads of current tile done
    if (pfm) {
      stK(0, nk0h, nk0l); stK(1, nk1h, nk1l);
      stV(0, nv0h, nv0l); stV(1, nv1h, nv1l);
    }
    __syncthreads();   // next tile ready
  }

  // ================= split-K merge =================
  if (lane < 32) {
    aM[kg * 64 + qw * 32 + l31] = mrun;
    aZ[kg * 64 + qw * 32 + l31] = Z;
  }
  if (kg == 1) {   // group B parks its O in Har
#pragma unroll
    for (int r = 0; r < 16; ++r) {
      const int qq = qw * 32 + (r & 3) + 8 * (r >> 2) + 4 * half;
      Har[qq * 68 + l31]      = o0[r];
      Har[qq * 68 + l31 + 32] = o1[r];
    }
  }
  __syncthreads();
  if (kg == 1 && lane < 32) {   // per-q merge factors
    const int q = qw * 32 + l31;
    const float ma = aM[q], mb = mrun;
    const float m  = fmaxf(ma, mb);
    const float fa = __expf(ma - m), fb = __expf(mb - m);
    const float Zs = aZ[q] * fa + Z * fb;
    aF[q]       = fa;
    aF[64 + q]  = fb;
    aF[128 + q] = 1.0f / (8.0f * Zs);   // sqrt(64)=8
  }
  __syncthreads();
  if (kg == 0) {   // group A merges into Har
#pragma unroll
    for (int r = 0; r < 16; ++r) {
      const int qq = qw * 32 + (r & 3) + 8 * (r >> 2) + 4 * half;
      const float fa = aF[qq], fb = aF[64 + qq];
      Har[qq * 68 + l31]      = o0[r] * fa + Har[qq * 68 + l31]      * fb;
      Har[qq * 68 + l31 + 32] = o1[r] * fa + Har[qq * 68 + l31 + 32] * fb;
    }
  }
  __syncthreads();

  // ================= epilogue (v2-verified 16x16 path, 16 rows/wave) ======
  const int g  = lane >> 4;
  const int ql = lane & 15;
  const int er = wave * 16;                   // block-relative first row
  const float i8z = aF[128 + er + ql];        // 1/(8 Z*) for q = er+ql

  bf16x8 hh[2], hl[2];
#pragma unroll
  for (int kk = 0; kk < 2; ++kk) {
    const float* hp = &Har[(er + ql) * 68 + kk * 32 + g * 8];
    float4 v0 = *(const float4*)hp;
    float4 v1 = *(const float4*)(hp + 4);
    float v[8] = {v0.x*i8z, v0.y*i8z, v0.z*i8z, v0.w*i8z,
                  v1.x*i8z, v1.y*i8z, v1.z*i8z, v1.w*i8z};
#pragma unroll
    for (int e = 0; e < 8; ++e) { short a, b; splitv(v[e], a, b); hh[kk][e] = a; hl[kk][e] = b; }
  }

  f32x4 lin[4];
#pragma unroll
  for (int c = 0; c < 4; ++c) {
    bf16x8 wh[2], wl[2];
#pragma unroll
    for (int kk = 0; kk < 2; ++kk) {
      const float* wp = W + (size_t)(c * 16 + ql) * kD + kk * 32 + g * 8;
      float4 v0 = *(const float4*)wp;
      float4 v1 = *(const float4*)(wp + 4);
      float v[8] = {v0.x, v0.y, v0.z, v0.w, v1.x, v1.y, v1.z, v1.w};
#pragma unroll
      for (int e = 0; e < 8; ++e) { short a, b; splitv(v[e], a, b); wh[kk][e] = a; wl[kk][e] = b; }
    }
    f32x4 acc = {0.f, 0.f, 0.f, 0.f};
    acc = MFMA16(hh[0], wh[0], acc);
    acc = MFMA16(hh[1], wh[1], acc);
    acc = MFMA16(hh[0], wl[0], acc);
    acc = MFMA16(hh[1], wl[1], acc);
    acc = MFMA16(hl[0], wh[0], acc);
    acc = MFMA16(hl[1], wh[1], acc);
    lin[c] = acc;
  }

  float rl[4][4];
#pragma unroll
  for (int c = 0; c < 4; ++c)
#pragma unroll
    for (int r = 0; r < 4; ++r) rl[c][r] = fmaxf(lin[c][r], 0.f);

  float mu[4], rstd[4];
#pragma unroll
  for (int r = 0; r < 4; ++r) {
    float s1 = rl[0][r] + rl[1][r] + rl[2][r] + rl[3][r];
    float s2 = rl[0][r]*rl[0][r] + rl[1][r]*rl[1][r] + rl[2][r]*rl[2][r] + rl[3][r]*rl[3][r];
#pragma unroll
    for (int off = 1; off < 16; off <<= 1) {
      s1 += __shfl_xor(s1, off, 64);
      s2 += __shfl_xor(s2, off, 64);
    }
    mu[r] = s1 * (1.f / 64.f);
    const float var = s2 * (1.f / 64.f) - mu[r] * mu[r];
    rstd[r] = rsqrtf(var + 1e-5f);
  }

#pragma unroll
  for (int c = 0; c < 4; ++c) {
    const float gm = gamma[c * 16 + ql];
    const float bb = beta[c * 16 + ql];
#pragma unroll
    for (int r = 0; r < 4; ++r) {
      const int qrow = qblk + er + 4 * g + r;
      const size_t off = ((size_t)bt * kN + qrow) * kD + c * 16 + ql;
      out[off] = (rl[c][r] - mu[r]) * rstd[r] * gm + bb + X[off];
    }
  }
}

extern "C" void kernel_launch(void* const* d_in, const int* in_sizes, int n_in,
                              void* d_out, int out_size, void* d_ws, size_t ws_size,
                              hipStream_t stream) {
  const float* X     = (const float*)d_in[0];
  const float* A     = (const float*)d_in[1];
  const float* W     = (const float*)d_in[2];
  const float* gamma = (const float*)d_in[3];
  const float* beta  = (const float*)d_in[4];
  float* out = (float*)d_out;

  short* Xh  = (short*)d_ws;
  short* Xl  = Xh  + kPlane;
  short* XTh = Xl  + kPlane;
  short* XTl = XTh + kPlane;

  presplit<<<dim3(48 * 16), 256, 0, stream>>>(X, Xh, Xl, XTh, XTl);
  sdgcn_v5<<<dim3(48 * 16), 256, 0, stream>>>(X, A, W, gamma, beta, out,
                                              Xh, Xl, XTh, XTl);
}